// Round 4
// baseline (671.715 us; speedup 1.0000x reference)
//
#include <hip/hip_runtime.h>
#include <hip/hip_bf16.h>

// Problem constants (from reference): B=64, S=2048, D_ENC=D_DEC=UNITS=512
#define BATCH 64
#define SEQ   2048
#define DIM   512
#define MROWS (BATCH * SEQ)   // 131072 rows of the big GEMM

typedef short bf16x8 __attribute__((ext_vector_type(8)));
typedef float f32x4  __attribute__((ext_vector_type(4)));

static __device__ __forceinline__ unsigned short f2bf(float f) {
    // round-to-nearest-even fp32 -> bf16
    union { float f; unsigned u; } v; v.f = f;
    unsigned u = v.u;
    u += 0x7FFFu + ((u >> 16) & 1u);
    return (unsigned short)(u >> 16);
}

// pack two fp32 -> bf16x2 with round-half-up (1 add + pack per elem; bias
// negligible vs RNE, max err identical 0.5 ulp)
static __device__ __forceinline__ unsigned pack_bf16_hu(float a, float b) {
    union { float f; unsigned u; } x, y; x.f = a; y.f = b;
    return ((y.u + 0x8000u) & 0xFFFF0000u) | ((x.u + 0x8000u) >> 16);
}

// fast tanh: tanh(x) = (e^{2x}-1)/(e^{2x}+1)
static __device__ __forceinline__ float tanh_fast(float x) {
    float xc = fminf(20.0f, fmaxf(-20.0f, x));
    float t = exp2f(2.885390082f * xc);   // e^{2x}
    return (t - 1.0f) / (t + 1.0f);
}

// global -> LDS async DMA, 16B per lane (dest = wave-uniform base + lane*16)
typedef __attribute__((address_space(1))) const unsigned int gu32;
typedef __attribute__((address_space(3))) unsigned int lu32;
static __device__ __forceinline__ void gload_lds16(const unsigned short* g,
                                                   unsigned short* l) {
    __builtin_amdgcn_global_load_lds((gu32*)g, (lu32*)l, 16, 0, 0);
}

// ---------------------------------------------------------------------------
// Kernel 0: W1 [k][u] fp32  ->  W1t [u][k] bf16   (512x512, tiny)
// ---------------------------------------------------------------------------
__global__ void prep_w1t_kernel(const float* __restrict__ W1,
                                unsigned short* __restrict__ w1t) {
    int stride = gridDim.x * blockDim.x;
    for (int i = blockIdx.x * blockDim.x + threadIdx.x; i < DIM * DIM; i += stride) {
        int k = i >> 9;
        int u = i & 511;
        w1t[u * DIM + k] = f2bf(W1[i]);
    }
}

// ---------------------------------------------------------------------------
// Kernel 1: pd[b][u] = dec[b,:] @ W2[:,u] + b1[u] + b2[u]
// grid (64 batches, 4 u-quarters) x 128 threads for parallelism.
// ---------------------------------------------------------------------------
__global__ void proj_dec_kernel(const float* __restrict__ dec,
                                const float* __restrict__ W2,
                                const float* __restrict__ b1,
                                const float* __restrict__ b2,
                                float* __restrict__ pd) {
    __shared__ float sdec[DIM];
    const int b  = blockIdx.x;
    const int u0 = blockIdx.y * 128;
    const int t  = threadIdx.x;          // 128 threads
    for (int i = t; i < DIM; i += 128) sdec[i] = dec[b * DIM + i];
    __syncthreads();
    const int u = u0 + t;
    float a = b1[u] + b2[u];
    for (int k = 0; k < DIM; ++k)
        a += sdec[k] * W2[k * DIM + u];
    pd[b * DIM + u] = a;
}

// ---------------------------------------------------------------------------
// Kernel 2 (v4): barrier-free K-loop GEMM + fused tanh/V epilogue.
//   block = 512 rows x 128 cols (one B column-quarter), 512 threads (8 waves),
//   wave = 64 rows x 128 cols (acc 8x4 f32x4 = 128 VGPR).
//   Prologue: B-quarter [128 u x 512 k] -> LDS (128 KB) ONCE via DMA with XOR
//   chunk swizzle; single barrier. K-loop (16 rounds of BK=32): A-frags loaded
//   straight from fp32 enc (half-up bf16 pack in-register, prefetched one
//   round ahead), B-frags ds_read_b128 from persistent LDS. No __syncthreads
//   in the loop. Epilogue: tanh_fast + V-dot, shuffle reduce, atomicAdd.
//   Dispatch map puts the 4 col-sibling blocks of a row-group on one XCD
//   (ids differ by 8 -> same id%8) so A hits XCD-L2 after first fetch.
// ---------------------------------------------------------------------------
__global__ __launch_bounds__(512, 2) void gemm_score_v4(
    const float* __restrict__ enc,            // [m][k] fp32
    const unsigned short* __restrict__ w1t,   // [u][k] bf16
    const float* __restrict__ pd,             // [b][u]
    const float* __restrict__ V,              // [u]
    float* __restrict__ scores)               // [M] pre-zeroed
{
    extern __shared__ unsigned short sB[];    // 128 rows x 64 chunks x 16 B = 128 KB

    const int tid  = threadIdx.x;
    const int lane = tid & 63;
    const int wave = tid >> 6;        // 0..7 -> 64-row slice
    const int quad = lane >> 4;
    const int l15  = lane & 15;

    // id -> (row-group rg 0..255, col-quarter cq 0..3); siblings share id%8
    const int id = blockIdx.x;               // 0..1023
    const int g  = id >> 5;                  // 0..31
    const int cq = (id >> 3) & 3;            // 0..3
    const int r8 = id & 7;                   // 0..7
    const int rg = g * 8 + r8;               // 0..255
    const int row0 = rg * 512;
    const int col0 = cq * 128;

    // ---- prologue: B-quarter -> LDS (8192 chunk-slots of 16 B, 16/thread)
    for (int i = 0; i < 16; ++i) {
        int s     = i * 512 + tid;
        int u     = s >> 6;                  // 0..127
        int cphys = s & 63;
        int clog  = cphys ^ (u & 7);
        gload_lds16(w1t + (size_t)(col0 + u) * DIM + clog * 8, &sB[(size_t)s * 8]);
    }

    f32x4 acc[8][4];   // [j: 16-col subtile][tr: 16-row subtile]
    for (int j = 0; j < 8; ++j)
        for (int tr = 0; tr < 4; ++tr)
            acc[j][tr] = (f32x4){0.f, 0.f, 0.f, 0.f};

    // A row base pointers for this wave (rows row0 + wave*64 + tr*16 + l15)
    const float* arow[4];
    for (int tr = 0; tr < 4; ++tr)
        arow[tr] = enc + (size_t)(row0 + wave * 64 + tr * 16 + l15) * DIM + quad * 8;

    // preload round 0 A raw
    float4 ar[4][2];
    for (int tr = 0; tr < 4; ++tr) {
        ar[tr][0] = *(const float4*)(arow[tr]);
        ar[tr][1] = *(const float4*)(arow[tr] + 4);
    }

    __syncthreads();   // B resident

    for (int r = 0; r < 16; ++r) {
        const int c = r * 4 + quad;   // logical k-chunk 0..63

        // B-frags from persistent LDS (swizzled): 2-way max bank aliasing
        bf16x8 bfr[8];
        for (int j = 0; j < 8; ++j) {
            int u = j * 16 + l15;
            bfr[j] = *(const bf16x8*)(&sB[(size_t)u * 64 * 8 + (size_t)(c ^ (u & 7)) * 8]);
        }

        // prefetch next round's A raw before the MFMA block
        float4 an[4][2];
        if (r < 15) {
            const int off = (r + 1) * 32;
            for (int tr = 0; tr < 4; ++tr) {
                an[tr][0] = *(const float4*)(arow[tr] + off);
                an[tr][1] = *(const float4*)(arow[tr] + off + 4);
            }
        }

        // convert current A raw -> bf16 frags
        bf16x8 af[4];
        for (int tr = 0; tr < 4; ++tr) {
            union { unsigned u[4]; bf16x8 v; } pk;
            pk.u[0] = pack_bf16_hu(ar[tr][0].x, ar[tr][0].y);
            pk.u[1] = pack_bf16_hu(ar[tr][0].z, ar[tr][0].w);
            pk.u[2] = pack_bf16_hu(ar[tr][1].x, ar[tr][1].y);
            pk.u[3] = pack_bf16_hu(ar[tr][1].z, ar[tr][1].w);
            af[tr] = pk.v;
        }

        for (int j = 0; j < 8; ++j)
            for (int tr = 0; tr < 4; ++tr)
                acc[j][tr] = __builtin_amdgcn_mfma_f32_16x16x32_bf16(
                    af[tr], bfr[j], acc[j][tr], 0, 0, 0);

        if (r < 15)
            for (int tr = 0; tr < 4; ++tr) {
                ar[tr][0] = an[tr][0];
                ar[tr][1] = an[tr][1];
            }
    }

    // ---- epilogue: tanh + V-dot over this block's 128 u's, partial -> atomic
    const int b = row0 >> 11;   // 512-row groups never cross a batch
    float sacc[4][4];
    for (int tr = 0; tr < 4; ++tr)
        for (int rr = 0; rr < 4; ++rr) sacc[tr][rr] = 0.f;

    for (int j = 0; j < 8; ++j) {
        int u_g   = col0 + j * 16 + l15;    // C/D col = lane&15
        float pdv = pd[b * DIM + u_g];
        float vv  = V[u_g];
        for (int tr = 0; tr < 4; ++tr)
            for (int rr = 0; rr < 4; ++rr)
                sacc[tr][rr] += tanh_fast(acc[j][tr][rr] + pdv) * vv;
    }
    for (int tr = 0; tr < 4; ++tr)
        for (int rr = 0; rr < 4; ++rr) {
            float v = sacc[tr][rr];
            v += __shfl_xor(v, 1);
            v += __shfl_xor(v, 2);
            v += __shfl_xor(v, 4);
            v += __shfl_xor(v, 8);
            sacc[tr][rr] = v;
        }
    if (l15 == 0) {
        for (int tr = 0; tr < 4; ++tr)
            for (int rr = 0; rr < 4; ++rr) {
                int m_g = row0 + wave * 64 + tr * 16 + quad * 4 + rr;  // C/D row
                atomicAdd(&scores[m_g], sacc[tr][rr]);
            }
    }
}

// ---------------------------------------------------------------------------
// Kernel 3: per-batch softmax over S=2048 -> attn (output)
// bv omitted: softmax is shift-invariant in both outputs.
// ---------------------------------------------------------------------------
__global__ void softmax_kernel(const float* __restrict__ scores,
                               float* __restrict__ attn) {
    __shared__ float se[SEQ];
    __shared__ float red[256];
    const int b = blockIdx.x;
    const int t = threadIdx.x;
    const float* sc = scores + (size_t)b * SEQ;

    float v[8];
    float mx = -1e30f;
    for (int i = 0; i < 8; ++i) {
        v[i] = sc[t + i * 256];
        mx = fmaxf(mx, v[i]);
    }
    red[t] = mx;
    __syncthreads();
    for (int off = 128; off > 0; off >>= 1) {
        if (t < off) red[t] = fmaxf(red[t], red[t + off]);
        __syncthreads();
    }
    mx = red[0];
    __syncthreads();

    float sum = 0.f;
    for (int i = 0; i < 8; ++i) {
        float e = expf(v[i] - mx);
        se[t + i * 256] = e;
        sum += e;
    }
    red[t] = sum;
    __syncthreads();
    for (int off = 128; off > 0; off >>= 1) {
        if (t < off) red[t] += red[t + off];
        __syncthreads();
    }
    const float inv = 1.0f / red[0];
    for (int i = 0; i < 8; ++i)
        attn[(size_t)b * SEQ + t + i * 256] = se[t + i * 256] * inv;
}

// ---------------------------------------------------------------------------
// Kernel 4: context[b][d] = sum_s attn[b,s] * enc[b,s,d], fp32 float4 loads.
// grid (32 s-chunks of 64, 64 batches), 256 thr: 2 j-halves x 128 d-quads.
// ---------------------------------------------------------------------------
#define SCHUNK 64
__global__ void context_f4(const float* __restrict__ enc,
                           const float* __restrict__ attn,
                           float* __restrict__ ctx) {
    __shared__ float sa[SCHUNK];
    __shared__ float4 sred[256];
    const int c = blockIdx.x;   // 0..31
    const int b = blockIdx.y;   // 0..63
    const int t = threadIdx.x;  // 256
    if (t < SCHUNK) sa[t] = attn[(size_t)b * SEQ + c * SCHUNK + t];
    __syncthreads();
    const int jh = t >> 7;          // 0..1
    const int d4 = (t & 127) * 4;   // 4 fp32 per thread
    float4 a = {0.f, 0.f, 0.f, 0.f};
    const float* base = enc + ((size_t)b * SEQ + (size_t)c * SCHUNK) * DIM;
    for (int j = jh; j < SCHUNK; j += 2) {
        float w = sa[j];
        float4 v = *(const float4*)(base + (size_t)j * DIM + d4);
        a.x += w * v.x; a.y += w * v.y; a.z += w * v.z; a.w += w * v.w;
    }
    sred[t] = a;
    __syncthreads();
    if (t < 128) {
        float4 p = sred[t], q = sred[t + 128];
        atomicAdd(&ctx[b * DIM + d4 + 0], p.x + q.x);
        atomicAdd(&ctx[b * DIM + d4 + 1], p.y + q.y);
        atomicAdd(&ctx[b * DIM + d4 + 2], p.z + q.z);
        atomicAdd(&ctx[b * DIM + d4 + 3], p.w + q.w);
    }
}

// ---------------------------------------------------------------------------
// Launch
// ---------------------------------------------------------------------------
extern "C" void kernel_launch(void* const* d_in, const int* in_sizes, int n_in,
                              void* d_out, int out_size, void* d_ws, size_t ws_size,
                              hipStream_t stream) {
    const float* enc = (const float*)d_in[0];   // [64,2048,512]
    const float* dec = (const float*)d_in[1];   // [64,512]
    const float* W1  = (const float*)d_in[2];   // [512,512]
    const float* b1  = (const float*)d_in[3];   // [512]
    const float* W2  = (const float*)d_in[4];   // [512,512]
    const float* b2  = (const float*)d_in[5];   // [512]
    const float* V   = (const float*)d_in[6];   // [512,1]
    // d_in[7] = bv: dead (softmax shift-invariance)

    float* out  = (float*)d_out;
    float* ctx  = out;                 // [64,512]
    float* attn = out + BATCH * DIM;   // [64,2048]

    char* ws = (char*)d_ws;
    float* pd            = (float*)ws;                        // 131072 B
    unsigned short* w1t  = (unsigned short*)(ws + 131072);    // 524288 B
    float* scores        = (float*)(ws + 131072 + 524288);    // 524288 B

    hipMemsetAsync(scores, 0, (size_t)MROWS * 4, stream);
    hipMemsetAsync(ctx, 0, (size_t)BATCH * DIM * 4, stream);

    prep_w1t_kernel<<<256, 256, 0, stream>>>(W1, w1t);
    proj_dec_kernel<<<dim3(BATCH, 4), 128, 0, stream>>>(dec, W2, b1, b2, pd);
    gemm_score_v4<<<1024, 512, 131072, stream>>>(enc, w1t, pd, V, scores);
    softmax_kernel<<<BATCH, 256, 0, stream>>>(scores, attn);
    context_f4<<<dim3(SEQ / SCHUNK, BATCH), 256, 0, stream>>>(enc, attn, ctx);
}

// Round 5
// 636.051 us; speedup vs baseline: 1.0561x; 1.0561x over previous
//
#include <hip/hip_runtime.h>
#include <hip/hip_bf16.h>

// Problem constants (from reference): B=64, S=2048, D_ENC=D_DEC=UNITS=512
#define BATCH 64
#define SEQ   2048
#define DIM   512
#define MROWS (BATCH * SEQ)   // 131072 rows of the big GEMM

typedef short bf16x8 __attribute__((ext_vector_type(8)));
typedef float f32x4  __attribute__((ext_vector_type(4)));

static __device__ __forceinline__ unsigned short f2bf(float f) {
    // round-to-nearest-even fp32 -> bf16
    union { float f; unsigned u; } v; v.f = f;
    unsigned u = v.u;
    u += 0x7FFFu + ((u >> 16) & 1u);
    return (unsigned short)(u >> 16);
}

// pack two fp32 -> bf16x2 with round-half-up (1 add + shift/merge per pair)
static __device__ __forceinline__ unsigned pack_bf16_hu(float a, float b) {
    union { float f; unsigned u; } x, y; x.f = a; y.f = b;
    return ((y.u + 0x8000u) & 0xFFFF0000u) | ((x.u + 0x8000u) >> 16);
}

// fast tanh: tanh(x) = (e^{2x}-1)/(e^{2x}+1)
static __device__ __forceinline__ float tanh_fast(float x) {
    float xc = fminf(20.0f, fmaxf(-20.0f, x));
    float t = exp2f(2.885390082f * xc);   // e^{2x}
    return (t - 1.0f) / (t + 1.0f);
}

// global -> LDS async DMA, 16B per lane (dest = wave-uniform base + lane*16)
typedef __attribute__((address_space(1))) const unsigned int gu32;
typedef __attribute__((address_space(3))) unsigned int lu32;
static __device__ __forceinline__ void gload_lds16(const unsigned short* g,
                                                   unsigned short* l) {
    __builtin_amdgcn_global_load_lds((gu32*)g, (lu32*)l, 16, 0, 0);
}

// ---------------------------------------------------------------------------
// Kernel 0: W1 [k][u] fp32  ->  W1t [u][k] bf16   (512x512, tiny)
// ---------------------------------------------------------------------------
__global__ void prep_w1t_kernel(const float* __restrict__ W1,
                                unsigned short* __restrict__ w1t) {
    int stride = gridDim.x * blockDim.x;
    for (int i = blockIdx.x * blockDim.x + threadIdx.x; i < DIM * DIM; i += stride) {
        int k = i >> 9;
        int u = i & 511;
        w1t[u * DIM + k] = f2bf(W1[i]);
    }
}

// ---------------------------------------------------------------------------
// Kernel 1: pd[b][u] = dec[b,:] @ W2[:,u] + b1[u] + b2[u]
// grid (64 batches, 4 u-quarters) x 128 threads.
// ---------------------------------------------------------------------------
__global__ void proj_dec_kernel(const float* __restrict__ dec,
                                const float* __restrict__ W2,
                                const float* __restrict__ b1,
                                const float* __restrict__ b2,
                                float* __restrict__ pd) {
    __shared__ float sdec[DIM];
    const int b  = blockIdx.x;
    const int u0 = blockIdx.y * 128;
    const int t  = threadIdx.x;          // 128 threads
    for (int i = t; i < DIM; i += 128) sdec[i] = dec[b * DIM + i];
    __syncthreads();
    const int u = u0 + t;
    float a = b1[u] + b2[u];
    for (int k = 0; k < DIM; ++k)
        a += sdec[k] * W2[k * DIM + u];
    pd[b * DIM + u] = a;
}

// ---------------------------------------------------------------------------
// Kernel 2 (v5): barrier-free K-loop GEMM, spill-free edition.
//   block = 256 rows x 128 cols, 512 threads (8 waves), wave = 32 rows x 128
//   cols (acc 2x8 f32x4 = 64 VGPR — half of v4; v4's 128-VGPR acc + prefetch
//   arrays spilled ~580 MB to scratch, WRITE_SIZE counter round 4).
//   Prologue: B col-quarter [128 u x 512 k] -> 128 KB LDS ONCE (DMA + XOR
//   chunk swizzle), one barrier. K-loop (16 x BK=32): A read as fp32 straight
//   from enc into VGPRs (compiler pipelines these with fine-grained vmcnt,
//   unlike global_load_lds which forces vmcnt(0) at barriers), half-up bf16
//   pack, then per col-subtile: 1 ds_read_b128 + 2 MFMA (1 live B-frag).
//   No __syncthreads in the loop. Epilogue: tanh_fast + V-dot, shuffle
//   reduce, atomicAdd partials into scores.
//   Dispatch map: 4 col-sibling blocks of a row-group share id%8 -> same XCD
//   -> A fetched from HBM once (round-4 FETCH_SIZE 273 MB confirmed).
// ---------------------------------------------------------------------------
__global__ __launch_bounds__(512, 2) void gemm_score_v5(
    const float* __restrict__ enc,            // [m][k] fp32
    const unsigned short* __restrict__ w1t,   // [u][k] bf16
    const float* __restrict__ pd,             // [b][u]
    const float* __restrict__ V,              // [u]
    float* __restrict__ scores)               // [M] pre-zeroed
{
    extern __shared__ unsigned short sB[];    // 128 u x 64 chunks x 16 B = 128 KB

    const int tid  = threadIdx.x;
    const int lane = tid & 63;
    const int wave = tid >> 6;        // 0..7 -> 32-row slice
    const int quad = lane >> 4;
    const int l15  = lane & 15;

    // id -> (row-group rg 0..511, col-quarter cq 0..3); siblings share id%8
    const int id = blockIdx.x;               // 0..2047
    const int g  = id >> 5;                  // 0..63
    const int cq = (id >> 3) & 3;            // 0..3
    const int r8 = id & 7;                   // 0..7
    const int rg = g * 8 + r8;               // 0..511
    const int row0 = rg * 256;
    const int col0 = cq * 128;

    // ---- prologue: B-quarter -> LDS (8192 chunk-slots of 16 B, 16/thread)
    for (int i = 0; i < 16; ++i) {
        int s     = i * 512 + tid;
        int u     = s >> 6;                  // 0..127
        int cphys = s & 63;
        int clog  = cphys ^ (u & 7);
        gload_lds16(w1t + (size_t)(col0 + u) * DIM + clog * 8, &sB[(size_t)s * 8]);
    }

    f32x4 acc[8][2];   // [j: 16-col subtile][tr: 16-row subtile]
    for (int j = 0; j < 8; ++j)
        for (int tr = 0; tr < 2; ++tr)
            acc[j][tr] = (f32x4){0.f, 0.f, 0.f, 0.f};

    // A row base pointers for this wave (rows row0 + wave*32 + tr*16 + l15)
    const float* arow0 = enc + (size_t)(row0 + wave * 32 + l15) * DIM + quad * 8;
    const float* arow1 = arow0 + (size_t)16 * DIM;

    __syncthreads();   // B resident (drains the DMA)

    for (int r = 0; r < 16; ++r) {
        const int c = r * 4 + quad;   // logical k-chunk 0..63
        const int off = r * 32;

        // A raw fp32 (compiler schedules these early w/ fine-grained vmcnt)
        float4 a00 = *(const float4*)(arow0 + off);
        float4 a01 = *(const float4*)(arow0 + off + 4);
        float4 a10 = *(const float4*)(arow1 + off);
        float4 a11 = *(const float4*)(arow1 + off + 4);

        bf16x8 af[2];
        {
            union { unsigned u[4]; bf16x8 v; } pk;
            pk.u[0] = pack_bf16_hu(a00.x, a00.y);
            pk.u[1] = pack_bf16_hu(a00.z, a00.w);
            pk.u[2] = pack_bf16_hu(a01.x, a01.y);
            pk.u[3] = pack_bf16_hu(a01.z, a01.w);
            af[0] = pk.v;
            pk.u[0] = pack_bf16_hu(a10.x, a10.y);
            pk.u[1] = pack_bf16_hu(a10.z, a10.w);
            pk.u[2] = pack_bf16_hu(a11.x, a11.y);
            pk.u[3] = pack_bf16_hu(a11.z, a11.w);
            af[1] = pk.v;
        }

        for (int j = 0; j < 8; ++j) {
            int u = j * 16 + l15;
            bf16x8 bfr = *(const bf16x8*)(&sB[(size_t)u * 512 + (size_t)(c ^ (u & 7)) * 8]);
            acc[j][0] = __builtin_amdgcn_mfma_f32_16x16x32_bf16(af[0], bfr, acc[j][0], 0, 0, 0);
            acc[j][1] = __builtin_amdgcn_mfma_f32_16x16x32_bf16(af[1], bfr, acc[j][1], 0, 0, 0);
        }
    }

    // ---- epilogue: tanh + V-dot over this block's 128 u's, partial -> atomic
    const int b = row0 >> 11;   // 256-row groups never cross a batch
    float sacc[2][4];
    for (int tr = 0; tr < 2; ++tr)
        for (int rr = 0; rr < 4; ++rr) sacc[tr][rr] = 0.f;

    for (int j = 0; j < 8; ++j) {
        int u_g   = col0 + j * 16 + l15;    // C/D col = lane&15
        float pdv = pd[b * DIM + u_g];
        float vv  = V[u_g];
        for (int tr = 0; tr < 2; ++tr)
            for (int rr = 0; rr < 4; ++rr)
                sacc[tr][rr] += tanh_fast(acc[j][tr][rr] + pdv) * vv;
    }
    for (int tr = 0; tr < 2; ++tr)
        for (int rr = 0; rr < 4; ++rr) {
            float v = sacc[tr][rr];
            v += __shfl_xor(v, 1);
            v += __shfl_xor(v, 2);
            v += __shfl_xor(v, 4);
            v += __shfl_xor(v, 8);
            sacc[tr][rr] = v;
        }
    if (l15 == 0) {
        for (int tr = 0; tr < 2; ++tr)
            for (int rr = 0; rr < 4; ++rr) {
                int m_g = row0 + wave * 32 + tr * 16 + quad * 4 + rr;  // C/D row
                atomicAdd(&scores[m_g], sacc[tr][rr]);
            }
    }
}

// ---------------------------------------------------------------------------
// Kernel 3: per-batch softmax over S=2048 -> attn (output)
// bv omitted: softmax is shift-invariant in both outputs.
// ---------------------------------------------------------------------------
__global__ void softmax_kernel(const float* __restrict__ scores,
                               float* __restrict__ attn) {
    __shared__ float se[SEQ];
    __shared__ float red[256];
    const int b = blockIdx.x;
    const int t = threadIdx.x;
    const float* sc = scores + (size_t)b * SEQ;

    float v[8];
    float mx = -1e30f;
    for (int i = 0; i < 8; ++i) {
        v[i] = sc[t + i * 256];
        mx = fmaxf(mx, v[i]);
    }
    red[t] = mx;
    __syncthreads();
    for (int off = 128; off > 0; off >>= 1) {
        if (t < off) red[t] = fmaxf(red[t], red[t + off]);
        __syncthreads();
    }
    mx = red[0];
    __syncthreads();

    float sum = 0.f;
    for (int i = 0; i < 8; ++i) {
        float e = expf(v[i] - mx);
        se[t + i * 256] = e;
        sum += e;
    }
    red[t] = sum;
    __syncthreads();
    for (int off = 128; off > 0; off >>= 1) {
        if (t < off) red[t] += red[t + off];
        __syncthreads();
    }
    const float inv = 1.0f / red[0];
    for (int i = 0; i < 8; ++i)
        attn[(size_t)b * SEQ + t + i * 256] = se[t + i * 256] * inv;
}

// ---------------------------------------------------------------------------
// Kernel 4: context[b][d] = sum_s attn[b,s] * enc[b,s,d], fp32 float4 loads.
// grid (32 s-chunks of 64, 64 batches), 256 thr: 2 j-halves x 128 d-quads.
// ---------------------------------------------------------------------------
#define SCHUNK 64
__global__ void context_f4(const float* __restrict__ enc,
                           const float* __restrict__ attn,
                           float* __restrict__ ctx) {
    __shared__ float sa[SCHUNK];
    __shared__ float4 sred[256];
    const int c = blockIdx.x;   // 0..31
    const int b = blockIdx.y;   // 0..63
    const int t = threadIdx.x;  // 256
    if (t < SCHUNK) sa[t] = attn[(size_t)b * SEQ + c * SCHUNK + t];
    __syncthreads();
    const int jh = t >> 7;          // 0..1
    const int d4 = (t & 127) * 4;   // 4 fp32 per thread
    float4 a = {0.f, 0.f, 0.f, 0.f};
    const float* base = enc + ((size_t)b * SEQ + (size_t)c * SCHUNK) * DIM;
    for (int j = jh; j < SCHUNK; j += 2) {
        float w = sa[j];
        float4 v = *(const float4*)(base + (size_t)j * DIM + d4);
        a.x += w * v.x; a.y += w * v.y; a.z += w * v.z; a.w += w * v.w;
    }
    sred[t] = a;
    __syncthreads();
    if (t < 128) {
        float4 p = sred[t], q = sred[t + 128];
        atomicAdd(&ctx[b * DIM + d4 + 0], p.x + q.x);
        atomicAdd(&ctx[b * DIM + d4 + 1], p.y + q.y);
        atomicAdd(&ctx[b * DIM + d4 + 2], p.z + q.z);
        atomicAdd(&ctx[b * DIM + d4 + 3], p.w + q.w);
    }
}

// ---------------------------------------------------------------------------
// Launch
// ---------------------------------------------------------------------------
extern "C" void kernel_launch(void* const* d_in, const int* in_sizes, int n_in,
                              void* d_out, int out_size, void* d_ws, size_t ws_size,
                              hipStream_t stream) {
    const float* enc = (const float*)d_in[0];   // [64,2048,512]
    const float* dec = (const float*)d_in[1];   // [64,512]
    const float* W1  = (const float*)d_in[2];   // [512,512]
    const float* b1  = (const float*)d_in[3];   // [512]
    const float* W2  = (const float*)d_in[4];   // [512,512]
    const float* b2  = (const float*)d_in[5];   // [512]
    const float* V   = (const float*)d_in[6];   // [512,1]
    // d_in[7] = bv: dead (softmax shift-invariance)

    float* out  = (float*)d_out;
    float* ctx  = out;                 // [64,512]
    float* attn = out + BATCH * DIM;   // [64,2048]

    char* ws = (char*)d_ws;
    float* pd            = (float*)ws;                        // 131072 B
    unsigned short* w1t  = (unsigned short*)(ws + 131072);    // 524288 B
    float* scores        = (float*)(ws + 131072 + 524288);    // 524288 B

    hipMemsetAsync(scores, 0, (size_t)MROWS * 4, stream);
    hipMemsetAsync(ctx, 0, (size_t)BATCH * DIM * 4, stream);

    prep_w1t_kernel<<<256, 256, 0, stream>>>(W1, w1t);
    proj_dec_kernel<<<dim3(BATCH, 4), 128, 0, stream>>>(dec, W2, b1, b2, pd);
    gemm_score_v5<<<2048, 512, 131072, stream>>>(enc, w1t, pd, V, scores);
    softmax_kernel<<<BATCH, 256, 0, stream>>>(scores, attn);
    context_f4<<<dim3(SEQ / SCHUNK, BATCH), 256, 0, stream>>>(enc, attn, ctx);
}